// Round 2
// baseline (400.578 us; speedup 1.0000x reference)
//
#include <hip/hip_runtime.h>

#define NCH   96
#define RF    25
#define HALF  12
#define HW    55
#define PLANE (HW * HW)   // 3025
#define CAP   32          // max compact taps per channel; dense fallback beyond
#define MAXA  4           // max active channels per 48-ch half on fast path
#define NGRP  12          // float4 groups per half (48 ch)

// d_ws layout:
//   int   counts[NCH]            @ 0        (384 B)
//   int   tap_off[NCH][CAP]      @ 384      (12288 B)  packed (dy<<8)|dx
//   float tap_w [NCH][CAP]       @ 12672    (12288 B)
//   int   meta[3 + 2*MAXA]       @ 24960    (flag, na[2], ch lists)
#define WS_META_OFF (NCH * 4 + NCH * CAP * 4 * 2)

// Single prep launch: 16 waves scan 6 channels each (ballot-compaction),
// then thread 0 builds per-half active-channel meta lists.
__global__ __launch_bounds__(1024) void prep_all(
        const float* __restrict__ kern, int* __restrict__ counts,
        int* __restrict__ tap_off, float* __restrict__ tap_w,
        int* __restrict__ meta) {
    __shared__ int scnt[NCH];
    const int wave = threadIdx.x >> 6;
    const int lane = threadIdx.x & 63;
    for (int c = wave; c < NCH; c += 16) {
        const float* kc = kern + c * (RF * RF);
        int base = 0;
        for (int seg = 0; seg < RF * RF; seg += 64) {
            const int i = seg + lane;
            const float w = (i < RF * RF) ? kc[i] : 0.0f;
            const unsigned long long m = __ballot(w != 0.0f);
            const int pos = base + __popcll(m & ((1ull << lane) - 1ull));
            if (w != 0.0f && pos < CAP) {
                const int dy = i / RF, dx = i - dy * RF;
                tap_off[c * CAP + pos] = (dy << 8) | dx;
                tap_w[c * CAP + pos]   = w;
            }
            base += __popcll(m);
        }
        if (lane == 0) { counts[c] = base; scnt[c] = base; }
    }
    __syncthreads();
    if (threadIdx.x == 0) {
        int na[2] = {0, 0};
        bool fallback = false;
        for (int ch = 0; ch < NCH; ++ch) {
            if (scnt[ch] > 0) {
                if (scnt[ch] > CAP) fallback = true;
                const int h = ch / 48;
                if (na[h] < MAXA) meta[3 + h * MAXA + na[h]] = ch;
                ++na[h];
            }
        }
        if (na[0] > MAXA || na[1] > MAXA) fallback = true;
        meta[0] = fallback ? 999 : 0;
        meta[1] = na[0] < MAXA ? na[0] : MAXA;
        meta[2] = na[1] < MAXA ? na[1] : MAXA;
        for (int h = 0; h < 2; ++h)
            for (int i = na[h]; i < MAXA; ++i) meta[3 + h * MAXA + i] = 0;
    }
}

// Block = (image n, channel-half h). Grid 256 = 1 block/CU.
// Half h owns channels [h*48, h*48+48) = bytes [h*192, h*192+192) of each
// pixel record — 64B-sector aligned, so blocks are data-disjoint and every
// output sector is written fully by exactly one sweep (no HBM RMW).
//   sweep1: coalesced read of own 12 groups; extract actives from the
//           stream registers into sh (full 55x55 plane, NO halo); write
//           out=x for sectors with no active channel.
//   conv  : dense lateral into lat[4][3025] (both-dim bounds checks).
//   sweep2: deferred sectors only: re-read float4s (L2/L3-hot), add lat
//           to active lanes, write the full sector once.
__global__ __launch_bounds__(1024, 4) void contour_img(
        const float* __restrict__ x, const float* __restrict__ kern,
        const int* __restrict__ counts, const int* __restrict__ tap_off,
        const float* __restrict__ tap_w, const int* __restrict__ meta,
        float* __restrict__ out) {
    __shared__ float sh[MAXA][HW][56];     // 49,280 B
    __shared__ float lat[MAXA * PLANE];    // 48,400 B
    __shared__ float tw[MAXA][CAP];
    __shared__ int   toff[MAXA][CAP];
    __shared__ int   tcnt[MAXA];
    __shared__ signed char c2l[48];        // local channel -> a (or -1)
    __shared__ int   wrNow[NGRP];          // group written in sweep1?
    __shared__ int   dsec[3];              // deferred local sectors (sorted)
    __shared__ int   ndsS;

    const int tid = threadIdx.x;
    const int b   = blockIdx.x;
    const int n   = b >> 1;
    const int h   = b & 1;

    const float* xn = x   + (size_t)n * (PLANE * NCH);
    float*       on = out + (size_t)n * (PLANE * NCH);

    const bool fast = (meta[0] != 999);
    const int  na   = fast ? meta[1 + h] : 0;

    // ---- phase 0: tables ----
    if (tid < 48) c2l[tid] = -1;
    __syncthreads();
    if (fast) {
        if (tid < na) {
            const int c = meta[3 + h * MAXA + tid];
            tcnt[tid] = counts[c];
            c2l[c - h * 48] = (signed char)tid;
        }
        if (tid >= 64 && tid < 64 + MAXA * CAP) {
            const int a = (tid - 64) / CAP, t = (tid - 64) % CAP;
            const int c = (a < na) ? meta[3 + h * MAXA + a] : h * 48;
            toff[a][t] = tap_off[c * CAP + t];
            tw[a][t]   = tap_w[c * CAP + t];
        }
    }
    __syncthreads();
    if (fast && tid == 0) {
        int nds = 0;
        for (int s = 0; s < 3; ++s) {            // 3 local 64B sectors
            bool act = false;
            for (int c = s * 16; c < s * 16 + 16; ++c) act |= (c2l[c] >= 0);
            for (int g = s * 4; g < s * 4 + 4; ++g) wrNow[g] = act ? 0 : 1;
            if (act) dsec[nds++] = s;
        }
        ndsS = nds;
    }
    __syncthreads();

    if (fast) {
        const float4* xs = (const float4*)xn;
        float4*       os = (float4*)on;
        const int base = h * NGRP;

        // ---- sweep 1: stream + in-register extraction + clean-sector write ----
        #pragma unroll 2
        for (int idx = tid; idx < PLANE * NGRP; idx += 1024) {
            const int px = idx / NGRP;
            const int gg = idx - px * NGRP;
            const int fi = px * 24 + base + gg;
            const float4 v = xs[fi];
            const int r = px / HW, col = px - r * HW;
            const int lc = gg * 4;
            const int a0 = c2l[lc + 0], a1 = c2l[lc + 1];
            const int a2 = c2l[lc + 2], a3 = c2l[lc + 3];
            if (a0 >= 0) sh[a0][r][col] = v.x;
            if (a1 >= 0) sh[a1][r][col] = v.y;
            if (a2 >= 0) sh[a2][r][col] = v.z;
            if (a3 >= 0) sh[a3][r][col] = v.w;
            if (wrNow[gg]) os[fi] = v;
        }
        __syncthreads();

        // ---- conv: dense, all lanes -> lat ----
        for (int idx = tid; idx < na * PLANE; idx += 1024) {
            const int a = idx / PLANE, p = idx - a * PLANE;
            const int r = p / HW, col = p - r * HW;
            const int cnt = tcnt[a];
            float acc = 0.0f;
            for (int t = 0; t < cnt; ++t) {
                const int off = toff[a][t];
                const float w = tw[a][t];
                const int yy = r   + (off >> 8)  - HALF;
                const int xx = col + (off & 255) - HALF;
                const bool ok = ((unsigned)yy < (unsigned)HW) &
                                ((unsigned)xx < (unsigned)HW);
                const int yc = min(max(yy, 0), HW - 1);
                const int xc = min(max(xx, 0), HW - 1);
                const float vv = sh[a][yc][xc];
                acc += ok ? w * vv : 0.0f;
            }
            lat[idx] = acc;
        }
        __syncthreads();

        // ---- sweep 2: deferred sectors, full-sector single write ----
        const int nds  = ndsS;
        const int tot2 = PLANE * nds * 4;
        for (int idx = tid; idx < tot2; idx += 1024) {
            const int px  = idx / (nds * 4);
            const int rem = idx - px * (nds * 4);
            const int d = rem >> 2, j = rem & 3;
            const int gg = dsec[d] * 4 + j;
            const int fi = px * 24 + base + gg;
            float4 v = xs[fi];                     // L2/L3-hot re-read
            const int lc = gg * 4;
            const int a0 = c2l[lc + 0], a1 = c2l[lc + 1];
            const int a2 = c2l[lc + 2], a3 = c2l[lc + 3];
            if (a0 >= 0) v.x += lat[a0 * PLANE + px];
            if (a1 >= 0) v.y += lat[a1 * PLANE + px];
            if (a2 >= 0) v.z += lat[a2 * PLANE + px];
            if (a3 >= 0) v.w += lat[a3 * PLANE + px];
            os[fi] = v;                            // full coverage, no RMW
        }
    } else {
        // ---- generic fallback (never taken for the reference mask) ----
        const float4* xs = (const float4*)xn;
        float4*       os = (float4*)on;
        for (int idx = tid; idx < PLANE * NGRP; idx += 1024) {
            const int px = idx / NGRP;
            const int gg = idx - px * NGRP;
            const int r  = px / HW, col = px - r * HW;
            const int fi = px * 24 + h * NGRP + gg;
            const float4 xv = xs[fi];
            float acc[4] = {xv.x, xv.y, xv.z, xv.w};
            for (int kk = 0; kk < 4; ++kk) {
                const int c = h * 48 + gg * 4 + kk;
                const int cnt = counts[c];
                if (cnt == 0) continue;
                float aa = 0.0f;
                if (cnt <= CAP) {
                    for (int t = 0; t < cnt; ++t) {
                        const int off = tap_off[c * CAP + t];
                        const float w = tap_w[c * CAP + t];
                        const int dy = off >> 8, dx = off & 255;
                        const int yy = r   + dy - HALF;
                        const int xx = col + dx - HALF;
                        if ((unsigned)yy < (unsigned)HW &&
                            (unsigned)xx < (unsigned)HW)
                            aa += w * xn[(size_t)(yy * HW + xx) * NCH + c];
                    }
                } else {
                    for (int dy = 0; dy < RF; ++dy)
                        for (int dx = 0; dx < RF; ++dx) {
                            const float w = kern[(c * RF + dy) * RF + dx];
                            if (w == 0.0f) continue;
                            const int yy = r   + dy - HALF;
                            const int xx = col + dx - HALF;
                            if ((unsigned)yy < (unsigned)HW &&
                                (unsigned)xx < (unsigned)HW)
                                aa += w * xn[(size_t)(yy * HW + xx) * NCH + c];
                        }
                }
                acc[kk] += aa;
            }
            os[fi] = make_float4(acc[0], acc[1], acc[2], acc[3]);
        }
    }
}

extern "C" void kernel_launch(void* const* d_in, const int* in_sizes, int n_in,
                              void* d_out, int out_size, void* d_ws, size_t ws_size,
                              hipStream_t stream) {
    const float* x    = (const float*)d_in[0];
    const float* kern = (const float*)d_in[1];
    float* out = (float*)d_out;

    int*   counts  = (int*)d_ws;
    int*   tap_off = (int*)((char*)d_ws + NCH * 4);
    float* tap_w   = (float*)((char*)d_ws + NCH * 4 + NCH * CAP * 4);
    int*   meta    = (int*)((char*)d_ws + WS_META_OFF);

    prep_all<<<1, 1024, 0, stream>>>(kern, counts, tap_off, tap_w, meta);

    // 128 images x 2 sector-aligned channel-halves; 256 blocks = 1 per CU
    contour_img<<<256, 1024, 0, stream>>>(x, kern, counts, tap_off, tap_w, meta, out);
}